// Round 12
// baseline (312.871 us; speedup 1.0000x reference)
//
#include <hip/hip_runtime.h>
#include <hip/hip_bf16.h>

#define NN 50000
#define NE 400000
#define AVG_LOG_F 2.1972245773362196f
#define EPSV 1e-5f

typedef __hip_bfloat16 bf16;
typedef __attribute__((ext_vector_type(8))) short short8v;
typedef __attribute__((ext_vector_type(4))) float f32x4;
typedef __attribute__((ext_vector_type(2))) _Float16 h2v;

__device__ __forceinline__ float b2f(bf16 v){ return __bfloat162float(v); }
__device__ __forceinline__ bf16  f2b(float v){ return __float2bfloat16(v); }
__device__ __forceinline__ short f2s(float v){
  bf16 b = __float2bfloat16(v);
  short s; __builtin_memcpy(&s, &b, 2); return s;
}
__device__ __forceinline__ short f2h(float v){
  _Float16 h = (_Float16)v;
  short s; __builtin_memcpy(&s, &h, 2); return s;
}

// ---------- h0b[n][d] = bf16( sum_c atom_emb[c][x[n][c]][d] ) ----------
__global__ void k_h0(const int* __restrict__ x, const float* __restrict__ aemb,
                     bf16* __restrict__ h0b){
  int idx = blockIdx.x * 256 + threadIdx.x;
  if (idx >= NN * 64) return;
  int n = idx >> 6, d = idx & 63;
  float acc = 0.f;
  #pragma unroll
  for (int c = 0; c < 9; ++c){
    int a = x[n * 9 + c];
    acc += aemb[(c * 64 + a) * 64 + d];
  }
  h0b[idx] = f2b(acc);
}

// ---------- degree histogram + bond code ----------
__global__ void k_deg_code(const int* __restrict__ ei, const int* __restrict__ ea,
                           int* __restrict__ deg, int* __restrict__ code){
  int e = blockIdx.x * 256 + threadIdx.x;
  if (e >= NE) return;
  int dst = ei[NE + e];
  atomicAdd(&deg[dst], 1);
  code[e] = ea[e * 3] + 8 * ea[e * 3 + 1] + 64 * ea[e * 3 + 2];
}

// ---------- exclusive scan of deg -> rowptr ----------
__global__ void k_scan1(const int* __restrict__ deg, int* __restrict__ rowptr,
                        int* __restrict__ part){
  __shared__ int s[256];
  int t = threadIdx.x, i = blockIdx.x * 256 + t;
  int v = (i < NN) ? deg[i] : 0;
  s[t] = v; __syncthreads();
  for (int off = 1; off < 256; off <<= 1){
    int xv = (t >= off) ? s[t - off] : 0;
    __syncthreads();
    s[t] += xv;
    __syncthreads();
  }
  if (i < NN) rowptr[i] = s[t] - v;
  if (t == 255) part[blockIdx.x] = s[255];
}

__global__ void k_scan2(int* __restrict__ part, int nblk){
  __shared__ int s[256];
  int t = threadIdx.x;
  int v = (t < nblk) ? part[t] : 0;
  s[t] = v; __syncthreads();
  for (int off = 1; off < 256; off <<= 1){
    int xv = (t >= off) ? s[t - off] : 0;
    __syncthreads();
    s[t] += xv;
    __syncthreads();
  }
  if (t < nblk) part[t] = s[t] - v;
}

__global__ void k_scan3(int* __restrict__ rowptr, const int* __restrict__ part,
                        const int* __restrict__ deg, float* __restrict__ amp,
                        float* __restrict__ att){
  int i = blockIdx.x * 256 + threadIdx.x;
  if (i < NN){
    rowptr[i] += part[blockIdx.x];
    int d = deg[i];
    float ld = logf((float)max(d, 1) + 1.0f);
    amp[i] = ld / AVG_LOG_F;
    att[i] = AVG_LOG_F / ld;
  }
  if (i == 0) rowptr[NN] = NE;
}

// ---------- scatter edges into CSR order, pre-multiplied byte offsets ----------
// sedge.x = src*1280 (node byte base in ABU), sedge.y = code*640 (byte base in CTp)
__global__ void k_scatter(const int* __restrict__ ei, const int* __restrict__ code,
                          const int* __restrict__ rowptr, int* __restrict__ cursor,
                          int2* __restrict__ sedge){
  int e = blockIdx.x * 256 + threadIdx.x;
  if (e >= NE) return;
  int dst = ei[NE + e];
  int pos = rowptr[dst] + atomicAdd(&cursor[dst], 1);
  int2 v; v.x = ei[e] * 1280; v.y = code[e] * 640;
  sedge[pos] = v;
}

// ---------- packed C table (fp16), split planes ----------
// CTp[code] (640B): bytes [0,512): lane d -> layers 0-3 (8B); [512,640): lane d -> layer 4 (2B)
__global__ void k_ctab(const float* __restrict__ bemb, const float* __restrict__ preW,
                       _Float16* __restrict__ CTp){
  __shared__ float et[64];
  int cb = blockIdx.x, l = blockIdx.y, t = threadIdx.x;
  int a0 = cb & 7, a1 = (cb >> 3) & 7, a2 = (cb >> 6) & 7;
  et[t] = bemb[(0 * 8 + a0) * 64 + t] + bemb[(1 * 8 + a1) * 64 + t] + bemb[(2 * 8 + a2) * 64 + t];
  __syncthreads();
  float acc = 0.f;
  const float* W = preW + (l * 192 + 128) * 64;
  for (int k = 0; k < 64; ++k) acc += et[k] * W[k * 64 + t];
  char* base = (char*)CTp + (size_t)cb * 640;
  if (l < 4) *(short*)(base + t * 8 + l * 2) = f2h(acc);
  else       *(short*)(base + 512 + t * 2)   = f2h(acc);
}

// ---------- Whsum / bias sums ----------
__global__ void k_whsum(const float* __restrict__ postW, const float* __restrict__ postb,
                        float* __restrict__ whs, float* __restrict__ bs){
  int idx = blockIdx.x * 256 + threadIdx.x;
  if (idx < 4096){
    int k = idx >> 6, d = idx & 63;
    float a = 0.f;
    for (int l = 0; l < 5; ++l) a += postW[(size_t)(l * 832 + 768 + k) * 64 + d];
    whs[idx] = a;
  }
  if (idx < 64){
    float a = 0.f;
    for (int l = 0; l < 5; ++l) a += postb[l * 64 + idx];
    bs[idx] = a;
  }
}

// ---------- WtKf: B-fragment-ready weights [s][g*4+w4][lane][8] ----------
__global__ void k_wtk(const float* __restrict__ postW, bf16* __restrict__ WtKf){
  int idx = blockIdx.x * 256 + threadIdx.x;
  if (idx >= 40 * 12 * 64 * 8) return;
  int s   = idx / 6144;
  int rem = idx % 6144;
  int gw  = rem / 512;
  int lane = (rem % 512) / 8;
  int j   = idx & 7;
  int g = gw >> 2, w4 = gw & 3;
  int kp = s * 32 + (lane >> 4) * 8 + j;
  int l = kp >> 8, kl = kp & 255;
  int c = w4 * 16 + (lane & 15);
  WtKf[idx] = f2b(postW[((size_t)l * 832 + g * 256 + kl) * 64 + c]);
}

// ---------- Wtp896[gc][k] + bias896 ----------
__global__ void k_wtpre896(const float* __restrict__ preW, const float* __restrict__ preb,
                           const float* __restrict__ whs, const float* __restrict__ bs,
                           bf16* __restrict__ Wtp, float* __restrict__ bias896){
  int idx = blockIdx.x * 256 + threadIdx.x;
  if (idx < 896 * 64){
    int gc = idx >> 6, k = idx & 63;
    float v;
    if (gc < 320){
      int l = gc >> 6, c = gc & 63;
      v = preW[(size_t)(l * 192 + k) * 64 + c];
    } else if (gc < 832){
      int q = gc - 320, d = q >> 3, l = q & 7;
      v = (l < 5) ? preW[(size_t)(l * 192 + 64 + k) * 64 + d] : 0.f;
    } else {
      int c = gc - 832;
      v = whs[k * 64 + c] + ((k == c) ? 1.f : 0.f);
    }
    Wtp[idx] = f2b(v);
  }
  if (idx < 896){
    float b;
    if (idx < 320)      b = preb[(idx >> 6) * 64 + (idx & 63)];
    else if (idx < 832) b = 0.f;
    else                b = bs[idx - 832];
    bias896[idx] = b;
  }
}

// ---------- ABU(fp16, split-plane)+out = h0b[N,64] @ Wtp896[64,896] via MFMA ----------
// ABU[n] (1280B): [0,640) A-part l*128+c*2; [640,1152) B8 d*8+l*2 (l<4); [1152,1280) B2 d*2 (l==4)
__global__ __launch_bounds__(256) void k_ab_mfma(const bf16* __restrict__ h0b,
                                                 const bf16* __restrict__ Wtp,
                                                 const float* __restrict__ bias896,
                                                 char* __restrict__ ABU,
                                                 float* __restrict__ out){
  __shared__ bf16 As[128][72];
  __shared__ bf16 Bs[128][72];
  const int t = threadIdx.x;
  const int n0 = blockIdx.x * 128;
  const int gc0 = blockIdx.y * 128;
  const int lane = t & 63, wid = t >> 6;
  const int rw = wid * 32;
  const short* H  = (const short*)h0b;
  const short* Wp = (const short*)Wtp;

  #pragma unroll
  for (int i = 0; i < 4; ++i){
    int idx = t + i * 256;
    int r = idx >> 3, ko = (idx & 7) * 8;
    int n = n0 + r;
    short8v v = short8v{0,0,0,0,0,0,0,0};
    if (n < NN) v = *(const short8v*)(H + (size_t)n * 64 + ko);
    *(short8v*)&As[r][ko] = v;
  }
  #pragma unroll
  for (int i = 0; i < 4; ++i){
    int idx = t + i * 256;
    int cc = idx >> 3, ko = (idx & 7) * 8;
    *(short8v*)&Bs[cc][ko] = *(const short8v*)(Wp + (size_t)(gc0 + cc) * 64 + ko);
  }
  __syncthreads();

  f32x4 acc[2][8] = {};
  #pragma unroll
  for (int kk = 0; kk < 2; ++kk){
    short8v af0 = *(const short8v*)&As[rw + (lane & 15)][kk * 32 + (lane >> 4) * 8];
    short8v af1 = *(const short8v*)&As[rw + 16 + (lane & 15)][kk * 32 + (lane >> 4) * 8];
    #pragma unroll
    for (int j = 0; j < 8; ++j){
      short8v bfj = *(const short8v*)&Bs[j * 16 + (lane & 15)][kk * 32 + (lane >> 4) * 8];
      acc[0][j] = __builtin_amdgcn_mfma_f32_16x16x32_bf16(af0, bfj, acc[0][j], 0, 0, 0);
      acc[1][j] = __builtin_amdgcn_mfma_f32_16x16x32_bf16(af1, bfj, acc[1][j], 0, 0, 0);
    }
  }

  #pragma unroll
  for (int i = 0; i < 2; ++i){
    #pragma unroll
    for (int r = 0; r < 4; ++r){
      int n = n0 + rw + i * 16 + (lane >> 4) * 4 + r;
      if (n >= NN) continue;
      char* nb = ABU + (size_t)n * 1280;
      #pragma unroll
      for (int j = 0; j < 8; ++j){
        int gc = gc0 + j * 16 + (lane & 15);
        float v = acc[i][j][r] + bias896[gc];
        if (gc < 320){
          *(short*)(nb + gc * 2) = f2h(v);
        } else if (gc < 832){
          int q = gc - 320, dd = q >> 3, l = q & 7;
          if (l < 4)       *(short*)(nb + 640 + dd * 8 + l * 2) = f2h(v);
          else if (l == 4) *(short*)(nb + 1152 + dd * 2)        = f2h(v);
          // l in {5,6,7}: padding column, not stored
        } else {
          out[(size_t)n * 64 + (gc - 832)] = v;
        }
      }
    }
  }
}

// ---------- gather: one node per wave, split-plane payload (8B+2B), batch-4 ----------
// AGG[n][l*256 + a*64 + d] bf16 (linear, coalesced)
__global__ __launch_bounds__(256) void k_gather(const char* __restrict__ ABU,
                                                const char* __restrict__ CTp,
                                                const int* __restrict__ rowptr,
                                                const int2* __restrict__ sedge,
                                                bf16* __restrict__ AGG){
  const int t = threadIdx.x, lane = t & 63, wid = t >> 6;
  const int n = blockIdx.x * 4 + wid;          // NN % 4 == 0, always valid
  const char* AB8 = ABU + 640;
  const char* AB2 = ABU + 1152;
  const char* CT8 = CTp;
  const char* CT2 = CTp + 512;
  short* AGs = (short*)AGG;

  int r0 = rowptr[n], r1 = rowptr[n + 1];
  float s[5]  = {0.f, 0.f, 0.f, 0.f, 0.f};
  float sq[5] = {0.f, 0.f, 0.f, 0.f, 0.f};
  const _Float16 FLO = (_Float16)(-65504.f);
  const _Float16 FHI = (_Float16)( 65504.f);
  h2v mx01 = h2v{FLO, FLO}, mx23 = h2v{FLO, FLO};
  h2v mn01 = h2v{FHI, FHI}, mn23 = h2v{FHI, FHI};
  float mx4 = -65504.f, mn4 = 65504.f;

  union U8 { uint2 u; h2v h[2]; };
  const int l8 = lane * 8, l2 = lane * 2;

  for (int j = r0; j < r1; j += 4){
    int rem = r1 - j;
    int2 e0 = sedge[j];
    int2 e1 = (rem > 1) ? sedge[j + 1] : e0;
    int2 e2 = (rem > 2) ? sedge[j + 2] : e0;
    int2 e3 = (rem > 3) ? sedge[j + 3] : e0;
    U8 a0, a1, a2, a3, c0, c1, c2, c3;
    unsigned short b0, b1, b2, b3, d0, d1, d2, d3;
    a0.u = *(const uint2*)(AB8 + e0.x + l8);  b0 = *(const unsigned short*)(AB2 + e0.x + l2);
    c0.u = *(const uint2*)(CT8 + e0.y + l8);  d0 = *(const unsigned short*)(CT2 + e0.y + l2);
    a1.u = *(const uint2*)(AB8 + e1.x + l8);  b1 = *(const unsigned short*)(AB2 + e1.x + l2);
    c1.u = *(const uint2*)(CT8 + e1.y + l8);  d1 = *(const unsigned short*)(CT2 + e1.y + l2);
    a2.u = *(const uint2*)(AB8 + e2.x + l8);  b2 = *(const unsigned short*)(AB2 + e2.x + l2);
    c2.u = *(const uint2*)(CT8 + e2.y + l8);  d2 = *(const unsigned short*)(CT2 + e2.y + l2);
    a3.u = *(const uint2*)(AB8 + e3.x + l8);  b3 = *(const unsigned short*)(AB2 + e3.x + l2);
    c3.u = *(const uint2*)(CT8 + e3.y + l8);  d3 = *(const unsigned short*)(CT2 + e3.y + l2);

    #define EDGE_ACC(A, C, BL, DL) {                                \
      h2v t01 = A.h[0] + C.h[0];                                    \
      h2v t23 = A.h[1] + C.h[1];                                    \
      _Float16 hb, hd;                                              \
      __builtin_memcpy(&hb, &BL, 2);                                \
      __builtin_memcpy(&hd, &DL, 2);                                \
      float f4 = (float)(hb + hd);                                  \
      mx01 = __builtin_elementwise_max(mx01, t01);                  \
      mx23 = __builtin_elementwise_max(mx23, t23);                  \
      mn01 = __builtin_elementwise_min(mn01, t01);                  \
      mn23 = __builtin_elementwise_min(mn23, t23);                  \
      mx4 = fmaxf(mx4, f4); mn4 = fminf(mn4, f4);                   \
      float f0 = (float)t01[0], f1 = (float)t01[1];                 \
      float f2 = (float)t23[0], f3 = (float)t23[1];                 \
      s[0] += f0; sq[0] = fmaf(f0, f0, sq[0]);                      \
      s[1] += f1; sq[1] = fmaf(f1, f1, sq[1]);                      \
      s[2] += f2; sq[2] = fmaf(f2, f2, sq[2]);                      \
      s[3] += f3; sq[3] = fmaf(f3, f3, sq[3]);                      \
      s[4] += f4; sq[4] = fmaf(f4, f4, sq[4]);                      \
    }
    EDGE_ACC(a0, c0, b0, d0);
    if (rem > 1) EDGE_ACC(a1, c1, b1, d1);
    if (rem > 2) EDGE_ACC(a2, c2, b2, d2);
    if (rem > 3) EDGE_ACC(a3, c3, b3, d3);
    #undef EDGE_ACC
  }

  float mx[5] = {(float)mx01[0], (float)mx01[1], (float)mx23[0], (float)mx23[1], mx4};
  float mn[5] = {(float)mn01[0], (float)mn01[1], (float)mn23[0], (float)mn23[1], mn4};

  int d = r1 - r0;
  float degc = (float)((d > 0) ? d : 1);
  size_t base = (size_t)n * 1280;
  const char* nb = ABU + (size_t)n * 1280;
  #pragma unroll
  for (int l = 0; l < 5; ++l){
    _Float16 Kh; __builtin_memcpy(&Kh, nb + l * 128 + lane * 2, 2);
    float K = (float)Kh;                                  // includes pre_b
    float mean = ((float)d * K + s[l]) / degc;
    float MX = (d > 0) ? (K + mx[l]) : 0.f;
    float MN = (d > 0) ? (K + mn[l]) : 0.f;
    float mu = s[l] / degc;
    float var = fmaxf(sq[l] / degc - mu * mu, 0.f);
    float sd = sqrtf(var + EPSV);
    AGs[base + l * 256 + lane]       = f2s(mean);
    AGs[base + l * 256 + 64 + lane]  = f2s(MX);
    AGs[base + l * 256 + 128 + lane] = f2s(MN);
    AGs[base + l * 256 + 192 + lane] = f2s(sd);
  }
}

// ---------- posttrans GEMM, fragment-direct + register double-buffered prefetch ----------
// block = 256 thr = 4 waves (w4 = col-slice); 32 rows (2 row-groups); depth-1 prefetch, unroll-2
__global__ __launch_bounds__(256) void k_post5(const bf16* __restrict__ AGG,
                                               const bf16* __restrict__ WtKf,
                                               const float* __restrict__ amp,
                                               const float* __restrict__ att,
                                               float* __restrict__ out){
  const int t = threadIdx.x, lane = t & 63, w4 = t >> 6;
  const int rg0 = blockIdx.x * 2;
  const char* pa0 = (const char*)AGG +
      ((size_t)(rg0 * 16) + (lane & 15)) * 2560 + (lane >> 4) * 16;
  const char* pa1 = pa0 + 16 * 2560;
  const char* pb  = (const char*)WtKf + w4 * 1024 + lane * 16;

  f32x4 acc[2][3] = {};
  short8v A0a, A1a, B0a, B1a, B2a, A0b, A1b, B0b, B1b, B2b;
  // prologue: slice 0 into buffer A
  A0a = *(const short8v*)pa0;
  A1a = *(const short8v*)pa1;
  B0a = *(const short8v*)pb;
  B1a = *(const short8v*)(pb + 4096);
  B2a = *(const short8v*)(pb + 8192);

  #define MFMA6(A0, A1, B0, B1, B2)                                          \
    acc[0][0] = __builtin_amdgcn_mfma_f32_16x16x32_bf16(A0, B0, acc[0][0], 0, 0, 0); \
    acc[0][1] = __builtin_amdgcn_mfma_f32_16x16x32_bf16(A0, B1, acc[0][1], 0, 0, 0); \
    acc[0][2] = __builtin_amdgcn_mfma_f32_16x16x32_bf16(A0, B2, acc[0][2], 0, 0, 0); \
    acc[1][0] = __builtin_amdgcn_mfma_f32_16x16x32_bf16(A1, B0, acc[1][0], 0, 0, 0); \
    acc[1][1] = __builtin_amdgcn_mfma_f32_16x16x32_bf16(A1, B1, acc[1][1], 0, 0, 0); \
    acc[1][2] = __builtin_amdgcn_mfma_f32_16x16x32_bf16(A1, B2, acc[1][2], 0, 0, 0);

  for (int k = 0; k < 19; ++k){
    // prefetch odd slice (2k+1) into buffer B
    A0b = *(const short8v*)(pa0 + 64);
    A1b = *(const short8v*)(pa1 + 64);
    B0b = *(const short8v*)(pb + 12288);
    B1b = *(const short8v*)(pb + 12288 + 4096);
    B2b = *(const short8v*)(pb + 12288 + 8192);
    MFMA6(A0a, A1a, B0a, B1a, B2a);            // slice 2k
    pa0 += 128; pa1 += 128; pb += 24576;
    // prefetch even slice (2k+2) into buffer A
    A0a = *(const short8v*)pa0;
    A1a = *(const short8v*)pa1;
    B0a = *(const short8v*)pb;
    B1a = *(const short8v*)(pb + 4096);
    B2a = *(const short8v*)(pb + 8192);
    MFMA6(A0b, A1b, B0b, B1b, B2b);            // slice 2k+1
  }
  // tail: slice 38 in buffer A; load slice 39 into buffer B
  A0b = *(const short8v*)(pa0 + 64);
  A1b = *(const short8v*)(pa1 + 64);
  B0b = *(const short8v*)(pb + 12288);
  B1b = *(const short8v*)(pb + 12288 + 4096);
  B2b = *(const short8v*)(pb + 12288 + 8192);
  MFMA6(A0a, A1a, B0a, B1a, B2a);
  MFMA6(A0b, A1b, B0b, B1b, B2b);
  #undef MFMA6

  // epilogue: out += U + amp*V + att*W  (C/D: col=lane&15, row=(lane>>4)*4+reg)
  #pragma unroll
  for (int i = 0; i < 2; ++i){
    #pragma unroll
    for (int r = 0; r < 4; ++r){
      int n = (rg0 + i) * 16 + (lane >> 4) * 4 + r;
      if (n >= NN) continue;
      float am = amp[n], at = att[n];
      int c = w4 * 16 + (lane & 15);
      out[(size_t)n * 64 + c] += acc[i][0][r] + am * acc[i][1][r] + at * acc[i][2][r];
    }
  }
}

extern "C" void kernel_launch(void* const* d_in, const int* in_sizes, int n_in,
                              void* d_out, int out_size, void* d_ws, size_t ws_size,
                              hipStream_t stream){
  const int*   x     = (const int*)d_in[0];
  const int*   ei    = (const int*)d_in[1];
  const int*   ea    = (const int*)d_in[2];
  const float* aemb  = (const float*)d_in[3];
  const float* bemb  = (const float*)d_in[4];
  const float* preW  = (const float*)d_in[5];
  const float* preb  = (const float*)d_in[6];
  const float* postW = (const float*)d_in[7];
  const float* postb = (const float*)d_in[8];
  float* out = (float*)d_out;

  char* p = (char*)d_ws;
  auto alloc = [&](size_t bytes) -> char* {
    char* r = p;
    p += (bytes + 255) & ~(size_t)255;
    return r;
  };
  bf16*      h0b     = (bf16*)     alloc((size_t)NN * 64 * 2);
  char*      ABU     = (char*)     alloc((size_t)NN * 1280);
  bf16*      AGG     = (bf16*)     alloc((size_t)(NN + 16) * 1280 * 2);  // +16 rows OOB pad
  int*       deg     = (int*)      alloc((size_t)NN * 4);
  int*       rowptr  = (int*)      alloc((size_t)(NN + 1) * 4);
  int*       cursor  = (int*)      alloc((size_t)NN * 4);
  float*     amp     = (float*)    alloc((size_t)NN * 4);
  float*     att     = (float*)    alloc((size_t)NN * 4);
  int*       code    = (int*)      alloc((size_t)NE * 4);
  int2*      sedge   = (int2*)     alloc((size_t)NE * 8);
  _Float16*  CTp     = (_Float16*) alloc((size_t)512 * 640);
  float*     whs     = (float*)    alloc((size_t)64 * 64 * 4);
  float*     bs      = (float*)    alloc((size_t)64 * 4);
  int*       part    = (int*)      alloc((size_t)256 * 4);
  bf16*      WtKf    = (bf16*)     alloc((size_t)40 * 12 * 64 * 8 * 2);
  bf16*      Wtp     = (bf16*)     alloc((size_t)896 * 64 * 2);
  float*     bias896 = (float*)    alloc((size_t)896 * 4);
  if ((size_t)(p - (char*)d_ws) > ws_size) return;

  hipMemsetAsync(deg, 0, (size_t)NN * 4, stream);
  hipMemsetAsync(cursor, 0, (size_t)NN * 4, stream);

  k_h0<<<dim3((NN * 64 + 255) / 256), 256, 0, stream>>>(x, aemb, h0b);
  k_deg_code<<<dim3((NE + 255) / 256), 256, 0, stream>>>(ei, ea, deg, code);
  int nblk = (NN + 255) / 256;
  k_scan1<<<dim3(nblk), 256, 0, stream>>>(deg, rowptr, part);
  k_scan2<<<dim3(1), 256, 0, stream>>>(part, nblk);
  k_scan3<<<dim3(nblk), 256, 0, stream>>>(rowptr, part, deg, amp, att);
  k_scatter<<<dim3((NE + 255) / 256), 256, 0, stream>>>(ei, code, rowptr, cursor, sedge);
  k_ctab<<<dim3(512, 5), 64, 0, stream>>>(bemb, preW, CTp);
  k_whsum<<<dim3(16), 256, 0, stream>>>(postW, postb, whs, bs);
  k_wtk<<<dim3((40 * 12 * 64 * 8 + 255) / 256), 256, 0, stream>>>(postW, WtKf);
  k_wtpre896<<<dim3((896 * 64 + 255) / 256), 256, 0, stream>>>(preW, preb, whs, bs,
                                                               Wtp, bias896);
  k_ab_mfma<<<dim3((NN + 127) / 128, 7), 256, 0, stream>>>(h0b, Wtp, bias896, ABU, out);
  k_gather<<<dim3(NN / 4), 256, 0, stream>>>(ABU, (const char*)CTp, rowptr, sedge, AGG);
  k_post5<<<dim3((3125 + 1) / 2), 256, 0, stream>>>(AGG, WtKf, amp, att, out);
}

// Round 13
// 277.371 us; speedup vs baseline: 1.1280x; 1.1280x over previous
//
#include <hip/hip_runtime.h>
#include <hip/hip_bf16.h>

#define NN 50000
#define NE 400000
#define AVG_LOG_F 2.1972245773362196f
#define EPSV 1e-5f

typedef __hip_bfloat16 bf16;
typedef __attribute__((ext_vector_type(8))) short short8v;
typedef __attribute__((ext_vector_type(4))) float f32x4;
typedef __attribute__((ext_vector_type(2))) _Float16 h2v;

__device__ __forceinline__ float b2f(bf16 v){ return __bfloat162float(v); }
__device__ __forceinline__ bf16  f2b(float v){ return __float2bfloat16(v); }
__device__ __forceinline__ short f2s(float v){
  bf16 b = __float2bfloat16(v);
  short s; __builtin_memcpy(&s, &b, 2); return s;
}
__device__ __forceinline__ short f2h(float v){
  _Float16 h = (_Float16)v;
  short s; __builtin_memcpy(&s, &h, 2); return s;
}

// ---------- h0b[n][d] = bf16( sum_c atom_emb[c][x[n][c]][d] ) ----------
__global__ void k_h0(const int* __restrict__ x, const float* __restrict__ aemb,
                     bf16* __restrict__ h0b){
  int idx = blockIdx.x * 256 + threadIdx.x;
  if (idx >= NN * 64) return;
  int n = idx >> 6, d = idx & 63;
  float acc = 0.f;
  #pragma unroll
  for (int c = 0; c < 9; ++c){
    int a = x[n * 9 + c];
    acc += aemb[(c * 64 + a) * 64 + d];
  }
  h0b[idx] = f2b(acc);
}

// ---------- degree histogram + bond code ----------
__global__ void k_deg_code(const int* __restrict__ ei, const int* __restrict__ ea,
                           int* __restrict__ deg, int* __restrict__ code){
  int e = blockIdx.x * 256 + threadIdx.x;
  if (e >= NE) return;
  int dst = ei[NE + e];
  atomicAdd(&deg[dst], 1);
  code[e] = ea[e * 3] + 8 * ea[e * 3 + 1] + 64 * ea[e * 3 + 2];
}

// ---------- exclusive scan of deg -> rowptr ----------
__global__ void k_scan1(const int* __restrict__ deg, int* __restrict__ rowptr,
                        int* __restrict__ part){
  __shared__ int s[256];
  int t = threadIdx.x, i = blockIdx.x * 256 + t;
  int v = (i < NN) ? deg[i] : 0;
  s[t] = v; __syncthreads();
  for (int off = 1; off < 256; off <<= 1){
    int xv = (t >= off) ? s[t - off] : 0;
    __syncthreads();
    s[t] += xv;
    __syncthreads();
  }
  if (i < NN) rowptr[i] = s[t] - v;
  if (t == 255) part[blockIdx.x] = s[255];
}

__global__ void k_scan2(int* __restrict__ part, int nblk){
  __shared__ int s[256];
  int t = threadIdx.x;
  int v = (t < nblk) ? part[t] : 0;
  s[t] = v; __syncthreads();
  for (int off = 1; off < 256; off <<= 1){
    int xv = (t >= off) ? s[t - off] : 0;
    __syncthreads();
    s[t] += xv;
    __syncthreads();
  }
  if (t < nblk) part[t] = s[t] - v;
}

__global__ void k_scan3(int* __restrict__ rowptr, const int* __restrict__ part,
                        const int* __restrict__ deg, float* __restrict__ amp,
                        float* __restrict__ att){
  int i = blockIdx.x * 256 + threadIdx.x;
  if (i < NN){
    rowptr[i] += part[blockIdx.x];
    int d = deg[i];
    float ld = logf((float)max(d, 1) + 1.0f);
    amp[i] = ld / AVG_LOG_F;
    att[i] = AVG_LOG_F / ld;
  }
  if (i == 0) rowptr[NN] = NE;
}

// ---------- scatter edges into CSR order, pre-multiplied byte offsets ----------
// sedge.x = src*1280 (node byte base in ABU), sedge.y = code*640 (byte base in CTp)
__global__ void k_scatter(const int* __restrict__ ei, const int* __restrict__ code,
                          const int* __restrict__ rowptr, int* __restrict__ cursor,
                          int2* __restrict__ sedge){
  int e = blockIdx.x * 256 + threadIdx.x;
  if (e >= NE) return;
  int dst = ei[NE + e];
  int pos = rowptr[dst] + atomicAdd(&cursor[dst], 1);
  int2 v; v.x = ei[e] * 1280; v.y = code[e] * 640;
  sedge[pos] = v;
}

// ---------- packed C table (fp16), split planes ----------
// CTp[code] (640B): bytes [0,512): lane d -> layers 0-3 (8B); [512,640): lane d -> layer 4 (2B)
__global__ void k_ctab(const float* __restrict__ bemb, const float* __restrict__ preW,
                       _Float16* __restrict__ CTp){
  __shared__ float et[64];
  int cb = blockIdx.x, l = blockIdx.y, t = threadIdx.x;
  int a0 = cb & 7, a1 = (cb >> 3) & 7, a2 = (cb >> 6) & 7;
  et[t] = bemb[(0 * 8 + a0) * 64 + t] + bemb[(1 * 8 + a1) * 64 + t] + bemb[(2 * 8 + a2) * 64 + t];
  __syncthreads();
  float acc = 0.f;
  const float* W = preW + (l * 192 + 128) * 64;
  for (int k = 0; k < 64; ++k) acc += et[k] * W[k * 64 + t];
  char* base = (char*)CTp + (size_t)cb * 640;
  if (l < 4) *(short*)(base + t * 8 + l * 2) = f2h(acc);
  else       *(short*)(base + 512 + t * 2)   = f2h(acc);
}

// ---------- Whsum / bias sums ----------
__global__ void k_whsum(const float* __restrict__ postW, const float* __restrict__ postb,
                        float* __restrict__ whs, float* __restrict__ bs){
  int idx = blockIdx.x * 256 + threadIdx.x;
  if (idx < 4096){
    int k = idx >> 6, d = idx & 63;
    float a = 0.f;
    for (int l = 0; l < 5; ++l) a += postW[(size_t)(l * 832 + 768 + k) * 64 + d];
    whs[idx] = a;
  }
  if (idx < 64){
    float a = 0.f;
    for (int l = 0; l < 5; ++l) a += postb[l * 64 + idx];
    bs[idx] = a;
  }
}

// ---------- WtKf: B-fragment-ready weights [s][g*4+w4][lane][8] ----------
__global__ void k_wtk(const float* __restrict__ postW, bf16* __restrict__ WtKf){
  int idx = blockIdx.x * 256 + threadIdx.x;
  if (idx >= 40 * 12 * 64 * 8) return;
  int s   = idx / 6144;
  int rem = idx % 6144;
  int gw  = rem / 512;
  int lane = (rem % 512) / 8;
  int j   = idx & 7;
  int g = gw >> 2, w4 = gw & 3;
  int kp = s * 32 + (lane >> 4) * 8 + j;
  int l = kp >> 8, kl = kp & 255;
  int c = w4 * 16 + (lane & 15);
  WtKf[idx] = f2b(postW[((size_t)l * 832 + g * 256 + kl) * 64 + c]);
}

// ---------- Wtp896[gc][k] + bias896 ----------
__global__ void k_wtpre896(const float* __restrict__ preW, const float* __restrict__ preb,
                           const float* __restrict__ whs, const float* __restrict__ bs,
                           bf16* __restrict__ Wtp, float* __restrict__ bias896){
  int idx = blockIdx.x * 256 + threadIdx.x;
  if (idx < 896 * 64){
    int gc = idx >> 6, k = idx & 63;
    float v;
    if (gc < 320){
      int l = gc >> 6, c = gc & 63;
      v = preW[(size_t)(l * 192 + k) * 64 + c];
    } else if (gc < 832){
      int q = gc - 320, d = q >> 3, l = q & 7;
      v = (l < 5) ? preW[(size_t)(l * 192 + 64 + k) * 64 + d] : 0.f;
    } else {
      int c = gc - 832;
      v = whs[k * 64 + c] + ((k == c) ? 1.f : 0.f);
    }
    Wtp[idx] = f2b(v);
  }
  if (idx < 896){
    float b;
    if (idx < 320)      b = preb[(idx >> 6) * 64 + (idx & 63)];
    else if (idx < 832) b = 0.f;
    else                b = bs[idx - 832];
    bias896[idx] = b;
  }
}

// ---------- ABU(fp16, split-plane)+out = h0b[N,64] @ Wtp896[64,896] via MFMA ----------
// ABU[n] (1280B): [0,640) A-part l*128+c*2; [640,1152) B8 d*8+l*2 (l<4); [1152,1280) B2 d*2 (l==4)
__global__ __launch_bounds__(256) void k_ab_mfma(const bf16* __restrict__ h0b,
                                                 const bf16* __restrict__ Wtp,
                                                 const float* __restrict__ bias896,
                                                 char* __restrict__ ABU,
                                                 float* __restrict__ out){
  __shared__ bf16 As[128][72];
  __shared__ bf16 Bs[128][72];
  const int t = threadIdx.x;
  const int n0 = blockIdx.x * 128;
  const int gc0 = blockIdx.y * 128;
  const int lane = t & 63, wid = t >> 6;
  const int rw = wid * 32;
  const short* H  = (const short*)h0b;
  const short* Wp = (const short*)Wtp;

  #pragma unroll
  for (int i = 0; i < 4; ++i){
    int idx = t + i * 256;
    int r = idx >> 3, ko = (idx & 7) * 8;
    int n = n0 + r;
    short8v v = short8v{0,0,0,0,0,0,0,0};
    if (n < NN) v = *(const short8v*)(H + (size_t)n * 64 + ko);
    *(short8v*)&As[r][ko] = v;
  }
  #pragma unroll
  for (int i = 0; i < 4; ++i){
    int idx = t + i * 256;
    int cc = idx >> 3, ko = (idx & 7) * 8;
    *(short8v*)&Bs[cc][ko] = *(const short8v*)(Wp + (size_t)(gc0 + cc) * 64 + ko);
  }
  __syncthreads();

  f32x4 acc[2][8] = {};
  #pragma unroll
  for (int kk = 0; kk < 2; ++kk){
    short8v af0 = *(const short8v*)&As[rw + (lane & 15)][kk * 32 + (lane >> 4) * 8];
    short8v af1 = *(const short8v*)&As[rw + 16 + (lane & 15)][kk * 32 + (lane >> 4) * 8];
    #pragma unroll
    for (int j = 0; j < 8; ++j){
      short8v bfj = *(const short8v*)&Bs[j * 16 + (lane & 15)][kk * 32 + (lane >> 4) * 8];
      acc[0][j] = __builtin_amdgcn_mfma_f32_16x16x32_bf16(af0, bfj, acc[0][j], 0, 0, 0);
      acc[1][j] = __builtin_amdgcn_mfma_f32_16x16x32_bf16(af1, bfj, acc[1][j], 0, 0, 0);
    }
  }

  #pragma unroll
  for (int i = 0; i < 2; ++i){
    #pragma unroll
    for (int r = 0; r < 4; ++r){
      int n = n0 + rw + i * 16 + (lane >> 4) * 4 + r;
      if (n >= NN) continue;
      char* nb = ABU + (size_t)n * 1280;
      #pragma unroll
      for (int j = 0; j < 8; ++j){
        int gc = gc0 + j * 16 + (lane & 15);
        float v = acc[i][j][r] + bias896[gc];
        if (gc < 320){
          *(short*)(nb + gc * 2) = f2h(v);
        } else if (gc < 832){
          int q = gc - 320, dd = q >> 3, l = q & 7;
          if (l < 4)       *(short*)(nb + 640 + dd * 8 + l * 2) = f2h(v);
          else if (l == 4) *(short*)(nb + 1152 + dd * 2)        = f2h(v);
          // l in {5,6,7}: padding column, not stored
        } else {
          out[(size_t)n * 64 + (gc - 832)] = v;
        }
      }
    }
  }
}

// ---------- gather: 16 waves/block, 1 node/wave; LDS transpose -> fragment-layout AGGf ----------
// AGGf chunk (g16, s): 1024B; lane holds row=lane&15 (node in group), k=s*32+(lane>>4)*8..+8
__global__ __launch_bounds__(1024, 8) void k_gather(const char* __restrict__ ABU,
                                                    const char* __restrict__ CTp,
                                                    const int* __restrict__ rowptr,
                                                    const int2* __restrict__ sedge,
                                                    bf16* __restrict__ AGGf){
  __shared__ __align__(16) short ag[16][1288];   // [node-in-group][l*256+a*64+d], +8 pad
  const int t = threadIdx.x, lane = t & 63, wid = t >> 6;   // wid 0..15
  const int n = blockIdx.x * 16 + wid;          // NN % 16 == 0, always valid
  const char* AB8 = ABU + 640;
  const char* AB2 = ABU + 1152;
  const char* CT8 = CTp;
  const char* CT2 = CTp + 512;

  int r0 = rowptr[n], r1 = rowptr[n + 1];
  float s[5]  = {0.f, 0.f, 0.f, 0.f, 0.f};
  float sq[5] = {0.f, 0.f, 0.f, 0.f, 0.f};
  const _Float16 FLO = (_Float16)(-65504.f);
  const _Float16 FHI = (_Float16)( 65504.f);
  h2v mx01 = h2v{FLO, FLO}, mx23 = h2v{FLO, FLO};
  h2v mn01 = h2v{FHI, FHI}, mn23 = h2v{FHI, FHI};
  float mx4 = -65504.f, mn4 = 65504.f;

  union U8 { uint2 u; h2v h[2]; };
  const int l8 = lane * 8, l2 = lane * 2;

  for (int j = r0; j < r1; j += 4){
    int rem = r1 - j;
    int2 e0 = sedge[j];
    int2 e1 = (rem > 1) ? sedge[j + 1] : e0;
    int2 e2 = (rem > 2) ? sedge[j + 2] : e0;
    int2 e3 = (rem > 3) ? sedge[j + 3] : e0;
    U8 a0, a1, a2, a3, c0, c1, c2, c3;
    unsigned short b0, b1, b2, b3, d0, d1, d2, d3;
    a0.u = *(const uint2*)(AB8 + e0.x + l8);  b0 = *(const unsigned short*)(AB2 + e0.x + l2);
    c0.u = *(const uint2*)(CT8 + e0.y + l8);  d0 = *(const unsigned short*)(CT2 + e0.y + l2);
    a1.u = *(const uint2*)(AB8 + e1.x + l8);  b1 = *(const unsigned short*)(AB2 + e1.x + l2);
    c1.u = *(const uint2*)(CT8 + e1.y + l8);  d1 = *(const unsigned short*)(CT2 + e1.y + l2);
    a2.u = *(const uint2*)(AB8 + e2.x + l8);  b2 = *(const unsigned short*)(AB2 + e2.x + l2);
    c2.u = *(const uint2*)(CT8 + e2.y + l8);  d2 = *(const unsigned short*)(CT2 + e2.y + l2);
    a3.u = *(const uint2*)(AB8 + e3.x + l8);  b3 = *(const unsigned short*)(AB2 + e3.x + l2);
    c3.u = *(const uint2*)(CT8 + e3.y + l8);  d3 = *(const unsigned short*)(CT2 + e3.y + l2);

    #define EDGE_ACC(A, C, BL, DL) {                                \
      h2v t01 = A.h[0] + C.h[0];                                    \
      h2v t23 = A.h[1] + C.h[1];                                    \
      _Float16 hb, hd;                                              \
      __builtin_memcpy(&hb, &BL, 2);                                \
      __builtin_memcpy(&hd, &DL, 2);                                \
      float f4 = (float)(hb + hd);                                  \
      mx01 = __builtin_elementwise_max(mx01, t01);                  \
      mx23 = __builtin_elementwise_max(mx23, t23);                  \
      mn01 = __builtin_elementwise_min(mn01, t01);                  \
      mn23 = __builtin_elementwise_min(mn23, t23);                  \
      mx4 = fmaxf(mx4, f4); mn4 = fminf(mn4, f4);                   \
      float f0 = (float)t01[0], f1 = (float)t01[1];                 \
      float f2 = (float)t23[0], f3 = (float)t23[1];                 \
      s[0] += f0; sq[0] = fmaf(f0, f0, sq[0]);                      \
      s[1] += f1; sq[1] = fmaf(f1, f1, sq[1]);                      \
      s[2] += f2; sq[2] = fmaf(f2, f2, sq[2]);                      \
      s[3] += f3; sq[3] = fmaf(f3, f3, sq[3]);                      \
      s[4] += f4; sq[4] = fmaf(f4, f4, sq[4]);                      \
    }
    EDGE_ACC(a0, c0, b0, d0);
    if (rem > 1) EDGE_ACC(a1, c1, b1, d1);
    if (rem > 2) EDGE_ACC(a2, c2, b2, d2);
    if (rem > 3) EDGE_ACC(a3, c3, b3, d3);
    #undef EDGE_ACC
  }

  float mx[5] = {(float)mx01[0], (float)mx01[1], (float)mx23[0], (float)mx23[1], mx4};
  float mn[5] = {(float)mn01[0], (float)mn01[1], (float)mn23[0], (float)mn23[1], mn4};

  int d = r1 - r0;
  float degc = (float)((d > 0) ? d : 1);
  const char* nb = ABU + (size_t)n * 1280;
  #pragma unroll
  for (int l = 0; l < 5; ++l){
    _Float16 Kh; __builtin_memcpy(&Kh, nb + l * 128 + lane * 2, 2);
    float K = (float)Kh;                                  // includes pre_b
    float mean = ((float)d * K + s[l]) / degc;
    float MX = (d > 0) ? (K + mx[l]) : 0.f;
    float MN = (d > 0) ? (K + mn[l]) : 0.f;
    float mu = s[l] / degc;
    float var = fmaxf(sq[l] / degc - mu * mu, 0.f);
    float sd = sqrtf(var + EPSV);
    ag[wid][l * 256 + lane]       = f2s(mean);
    ag[wid][l * 256 + 64 + lane]  = f2s(MX);
    ag[wid][l * 256 + 128 + lane] = f2s(MN);
    ag[wid][l * 256 + 192 + lane] = f2s(sd);
  }
  __syncthreads();

  // cooperative coalesced write: 2560 x 16B chunks -> AGGf fragment layout
  char* dst = (char*)AGGf + (size_t)blockIdx.x * 40960;
  for (int c = t; c < 2560; c += 1024){
    int ln = c & 63;
    int row = ln & 15;
    int k = (c >> 6) * 32 + (ln >> 4) * 8;
    short8v v = *(const short8v*)&ag[row][k];
    *(short8v*)(dst + (size_t)c * 16) = v;
  }
}

// ---------- posttrans GEMM, fragment-direct from AGGf, 64 rows/block, X/Y reg dbuf ----------
// 256 thr = 4 waves (w4 = col-slice); each wave: 4 node-groups x 3 col-groups, 12 MFMA/slice
__global__ __launch_bounds__(256, 2) void k_post5(const bf16* __restrict__ AGGf,
                                                  const bf16* __restrict__ WtKf,
                                                  const float* __restrict__ amp,
                                                  const float* __restrict__ att,
                                                  float* __restrict__ out){
  const int t = threadIdx.x, lane = t & 63, w4 = t >> 6;
  const long g0 = (long)blockIdx.x * 4;
  const char* pa = (const char*)AGGf + (size_t)g0 * 40960 + lane * 16;
  const char* pb = (const char*)WtKf + w4 * 1024 + lane * 16;

  f32x4 acc[4][3] = {};
  short8v Ax[4], Bx[3], Ay[4], By[3];

  #define LOADX(sidx) { \
    _Pragma("unroll") for (int gi = 0; gi < 4; ++gi) \
      Ax[gi] = *(const short8v*)(pa + (size_t)gi * 40960 + (size_t)(sidx) * 1024); \
    _Pragma("unroll") for (int g = 0; g < 3; ++g) \
      Bx[g] = *(const short8v*)(pb + (size_t)(sidx) * 12288 + g * 4096); }
  #define LOADY(sidx) { \
    _Pragma("unroll") for (int gi = 0; gi < 4; ++gi) \
      Ay[gi] = *(const short8v*)(pa + (size_t)gi * 40960 + (size_t)(sidx) * 1024); \
    _Pragma("unroll") for (int g = 0; g < 3; ++g) \
      By[g] = *(const short8v*)(pb + (size_t)(sidx) * 12288 + g * 4096); }
  #define MFMAX { \
    _Pragma("unroll") for (int gi = 0; gi < 4; ++gi){ \
      _Pragma("unroll") for (int g = 0; g < 3; ++g) \
        acc[gi][g] = __builtin_amdgcn_mfma_f32_16x16x32_bf16(Ax[gi], Bx[g], acc[gi][g], 0, 0, 0); } }
  #define MFMAY { \
    _Pragma("unroll") for (int gi = 0; gi < 4; ++gi){ \
      _Pragma("unroll") for (int g = 0; g < 3; ++g) \
        acc[gi][g] = __builtin_amdgcn_mfma_f32_16x16x32_bf16(Ay[gi], By[g], acc[gi][g], 0, 0, 0); } }

  LOADX(0);
  LOADY(1);
  for (int k = 0; k < 19; ++k){
    MFMAX;
    LOADX(2 * k + 2);
    MFMAY;
    LOADY(2 * k + 3);
  }
  MFMAX;
  MFMAY;
  #undef LOADX
  #undef LOADY
  #undef MFMAX
  #undef MFMAY

  // epilogue: out += U + amp*V + att*W  (C/D: col=lane&15, row=(lane>>4)*4+reg)
  #pragma unroll
  for (int gi = 0; gi < 4; ++gi){
    #pragma unroll
    for (int r = 0; r < 4; ++r){
      long n = (g0 + gi) * 16 + (lane >> 4) * 4 + r;
      if (n >= NN) continue;
      float am = amp[n], at = att[n];
      int c = w4 * 16 + (lane & 15);
      out[(size_t)n * 64 + c] += acc[gi][0][r] + am * acc[gi][1][r] + at * acc[gi][2][r];
    }
  }
}

extern "C" void kernel_launch(void* const* d_in, const int* in_sizes, int n_in,
                              void* d_out, int out_size, void* d_ws, size_t ws_size,
                              hipStream_t stream){
  const int*   x     = (const int*)d_in[0];
  const int*   ei    = (const int*)d_in[1];
  const int*   ea    = (const int*)d_in[2];
  const float* aemb  = (const float*)d_in[3];
  const float* bemb  = (const float*)d_in[4];
  const float* preW  = (const float*)d_in[5];
  const float* preb  = (const float*)d_in[6];
  const float* postW = (const float*)d_in[7];
  const float* postb = (const float*)d_in[8];
  float* out = (float*)d_out;

  char* p = (char*)d_ws;
  auto alloc = [&](size_t bytes) -> char* {
    char* r = p;
    p += (bytes + 255) & ~(size_t)255;
    return r;
  };
  bf16*      h0b     = (bf16*)     alloc((size_t)NN * 64 * 2);
  char*      ABU     = (char*)     alloc((size_t)NN * 1280);
  bf16*      AGGf    = (bf16*)     alloc((size_t)3128 * 40960);   // 3125 groups + 3 pad
  int*       deg     = (int*)      alloc((size_t)NN * 4);
  int*       rowptr  = (int*)      alloc((size_t)(NN + 1) * 4);
  int*       cursor  = (int*)      alloc((size_t)NN * 4);
  float*     amp     = (float*)    alloc((size_t)NN * 4);
  float*     att     = (float*)    alloc((size_t)NN * 4);
  int*       code    = (int*)      alloc((size_t)NE * 4);
  int2*      sedge   = (int2*)     alloc((size_t)NE * 8);
  _Float16*  CTp     = (_Float16*) alloc((size_t)512 * 640);
  float*     whs     = (float*)    alloc((size_t)64 * 64 * 4);
  float*     bs      = (float*)    alloc((size_t)64 * 4);
  int*       part    = (int*)      alloc((size_t)256 * 4);
  bf16*      WtKf    = (bf16*)     alloc((size_t)40 * 12 * 64 * 8 * 2);
  bf16*      Wtp     = (bf16*)     alloc((size_t)896 * 64 * 2);
  float*     bias896 = (float*)    alloc((size_t)896 * 4);
  if ((size_t)(p - (char*)d_ws) > ws_size) return;

  hipMemsetAsync(deg, 0, (size_t)NN * 4, stream);
  hipMemsetAsync(cursor, 0, (size_t)NN * 4, stream);

  k_h0<<<dim3((NN * 64 + 255) / 256), 256, 0, stream>>>(x, aemb, h0b);
  k_deg_code<<<dim3((NE + 255) / 256), 256, 0, stream>>>(ei, ea, deg, code);
  int nblk = (NN + 255) / 256;
  k_scan1<<<dim3(nblk), 256, 0, stream>>>(deg, rowptr, part);
  k_scan2<<<dim3(1), 256, 0, stream>>>(part, nblk);
  k_scan3<<<dim3(nblk), 256, 0, stream>>>(rowptr, part, deg, amp, att);
  k_scatter<<<dim3((NE + 255) / 256), 256, 0, stream>>>(ei, code, rowptr, cursor, sedge);
  k_ctab<<<dim3(512, 5), 64, 0, stream>>>(bemb, preW, CTp);
  k_whsum<<<dim3(16), 256, 0, stream>>>(postW, postb, whs, bs);
  k_wtk<<<dim3((40 * 12 * 64 * 8 + 255) / 256), 256, 0, stream>>>(postW, WtKf);
  k_wtpre896<<<dim3((896 * 64 + 255) / 256), 256, 0, stream>>>(preW, preb, whs, bs,
                                                               Wtp, bias896);
  k_ab_mfma<<<dim3((NN + 127) / 128, 7), 256, 0, stream>>>(h0b, Wtp, bias896, ABU, out);
  k_gather<<<dim3(NN / 16), 1024, 0, stream>>>(ABU, (const char*)CTp, rowptr, sedge, AGGf);
  k_post5<<<dim3(782), 256, 0, stream>>>(AGGf, WtKf, amp, att, out);
}

// Round 14
// 267.554 us; speedup vs baseline: 1.1694x; 1.0367x over previous
//
#include <hip/hip_runtime.h>
#include <hip/hip_bf16.h>

#define NN 50000
#define NE 400000
#define AVG_LOG_F 2.1972245773362196f
#define EPSV 1e-5f

typedef __hip_bfloat16 bf16;
typedef __attribute__((ext_vector_type(8))) short short8v;
typedef __attribute__((ext_vector_type(4))) float f32x4;
typedef __attribute__((ext_vector_type(2))) _Float16 h2v;

__device__ __forceinline__ float b2f(bf16 v){ return __bfloat162float(v); }
__device__ __forceinline__ bf16  f2b(float v){ return __float2bfloat16(v); }
__device__ __forceinline__ short f2s(float v){
  bf16 b = __float2bfloat16(v);
  short s; __builtin_memcpy(&s, &b, 2); return s;
}
__device__ __forceinline__ short f2h(float v){
  _Float16 h = (_Float16)v;
  short s; __builtin_memcpy(&s, &h, 2); return s;
}

// ---------- h0b[n][d] = bf16( sum_c atom_emb[c][x[n][c]][d] ) ----------
__global__ void k_h0(const int* __restrict__ x, const float* __restrict__ aemb,
                     bf16* __restrict__ h0b){
  int idx = blockIdx.x * 256 + threadIdx.x;
  if (idx >= NN * 64) return;
  int n = idx >> 6, d = idx & 63;
  float acc = 0.f;
  #pragma unroll
  for (int c = 0; c < 9; ++c){
    int a = x[n * 9 + c];
    acc += aemb[(c * 64 + a) * 64 + d];
  }
  h0b[idx] = f2b(acc);
}

// ---------- degree histogram + bond code ----------
__global__ void k_deg_code(const int* __restrict__ ei, const int* __restrict__ ea,
                           int* __restrict__ deg, int* __restrict__ code){
  int e = blockIdx.x * 256 + threadIdx.x;
  if (e >= NE) return;
  int dst = ei[NE + e];
  atomicAdd(&deg[dst], 1);
  code[e] = ea[e * 3] + 8 * ea[e * 3 + 1] + 64 * ea[e * 3 + 2];
}

// ---------- exclusive scan of deg -> rowptr ----------
__global__ void k_scan1(const int* __restrict__ deg, int* __restrict__ rowptr,
                        int* __restrict__ part){
  __shared__ int s[256];
  int t = threadIdx.x, i = blockIdx.x * 256 + t;
  int v = (i < NN) ? deg[i] : 0;
  s[t] = v; __syncthreads();
  for (int off = 1; off < 256; off <<= 1){
    int xv = (t >= off) ? s[t - off] : 0;
    __syncthreads();
    s[t] += xv;
    __syncthreads();
  }
  if (i < NN) rowptr[i] = s[t] - v;
  if (t == 255) part[blockIdx.x] = s[255];
}

__global__ void k_scan2(int* __restrict__ part, int nblk){
  __shared__ int s[256];
  int t = threadIdx.x;
  int v = (t < nblk) ? part[t] : 0;
  s[t] = v; __syncthreads();
  for (int off = 1; off < 256; off <<= 1){
    int xv = (t >= off) ? s[t - off] : 0;
    __syncthreads();
    s[t] += xv;
    __syncthreads();
  }
  if (t < nblk) part[t] = s[t] - v;
}

__global__ void k_scan3(int* __restrict__ rowptr, const int* __restrict__ part,
                        const int* __restrict__ deg, float* __restrict__ amp,
                        float* __restrict__ att){
  int i = blockIdx.x * 256 + threadIdx.x;
  if (i < NN){
    rowptr[i] += part[blockIdx.x];
    int d = deg[i];
    float ld = logf((float)max(d, 1) + 1.0f);
    amp[i] = ld / AVG_LOG_F;
    att[i] = AVG_LOG_F / ld;
  }
  if (i == 0) rowptr[NN] = NE;
}

// ---------- scatter edges into CSR order, pre-multiplied byte offsets ----------
// sedge.x = src*1280 (node byte base in ABU), sedge.y = code*640 (byte base in CTp)
__global__ void k_scatter(const int* __restrict__ ei, const int* __restrict__ code,
                          const int* __restrict__ rowptr, int* __restrict__ cursor,
                          int2* __restrict__ sedge){
  int e = blockIdx.x * 256 + threadIdx.x;
  if (e >= NE) return;
  int dst = ei[NE + e];
  int pos = rowptr[dst] + atomicAdd(&cursor[dst], 1);
  int2 v; v.x = ei[e] * 1280; v.y = code[e] * 640;
  sedge[pos] = v;
}

// ---------- packed C table (fp16), split planes ----------
// CTp[code] (640B): bytes [0,512): lane d -> layers 0-3 (8B); [512,640): lane d -> layer 4 (2B)
__global__ void k_ctab(const float* __restrict__ bemb, const float* __restrict__ preW,
                       _Float16* __restrict__ CTp){
  __shared__ float et[64];
  int cb = blockIdx.x, l = blockIdx.y, t = threadIdx.x;
  int a0 = cb & 7, a1 = (cb >> 3) & 7, a2 = (cb >> 6) & 7;
  et[t] = bemb[(0 * 8 + a0) * 64 + t] + bemb[(1 * 8 + a1) * 64 + t] + bemb[(2 * 8 + a2) * 64 + t];
  __syncthreads();
  float acc = 0.f;
  const float* W = preW + (l * 192 + 128) * 64;
  for (int k = 0; k < 64; ++k) acc += et[k] * W[k * 64 + t];
  char* base = (char*)CTp + (size_t)cb * 640;
  if (l < 4) *(short*)(base + t * 8 + l * 2) = f2h(acc);
  else       *(short*)(base + 512 + t * 2)   = f2h(acc);
}

// ---------- WtKf: B-fragment-ready weights [s][g*4+w4][lane][8] ----------
__global__ void k_wtk(const float* __restrict__ postW, bf16* __restrict__ WtKf){
  int idx = blockIdx.x * 256 + threadIdx.x;
  if (idx >= 40 * 12 * 64 * 8) return;
  int s   = idx / 6144;
  int rem = idx % 6144;
  int gw  = rem / 512;
  int lane = (rem % 512) / 8;
  int j   = idx & 7;
  int g = gw >> 2, w4 = gw & 3;
  int kp = s * 32 + (lane >> 4) * 8 + j;
  int l = kp >> 8, kl = kp & 255;
  int c = w4 * 16 + (lane & 15);
  WtKf[idx] = f2b(postW[((size_t)l * 832 + g * 256 + kl) * 64 + c]);
}

// ---------- Wtp896[gc][k] + bias896 (whsum folded inline) ----------
__global__ void k_wtpre896(const float* __restrict__ preW, const float* __restrict__ preb,
                           const float* __restrict__ postW, const float* __restrict__ postb,
                           bf16* __restrict__ Wtp, float* __restrict__ bias896){
  int idx = blockIdx.x * 256 + threadIdx.x;
  if (idx < 896 * 64){
    int gc = idx >> 6, k = idx & 63;
    float v;
    if (gc < 320){
      int l = gc >> 6, c = gc & 63;
      v = preW[(size_t)(l * 192 + k) * 64 + c];
    } else if (gc < 832){
      int q = gc - 320, d = q >> 3, l = q & 7;
      v = (l < 5) ? preW[(size_t)(l * 192 + 64 + k) * 64 + d] : 0.f;
    } else {
      int c = gc - 832;
      float a = 0.f;
      #pragma unroll
      for (int l = 0; l < 5; ++l) a += postW[(size_t)(l * 832 + 768 + k) * 64 + c];
      v = a + ((k == c) ? 1.f : 0.f);
    }
    Wtp[idx] = f2b(v);
  }
  if (idx < 896){
    float b;
    if (idx < 320)      b = preb[(idx >> 6) * 64 + (idx & 63)];
    else if (idx < 832) b = 0.f;
    else {
      float a = 0.f;
      #pragma unroll
      for (int l = 0; l < 5; ++l) a += postb[l * 64 + (idx - 832)];
      b = a;
    }
    bias896[idx] = b;
  }
}

// ---------- ABU(fp16, split-plane)+out = h0b[N,64] @ Wtp896[64,896] via MFMA ----------
// ABU[n] (1280B): [0,640) A-part l*128+c*2; [640,1152) B8 d*8+l*2 (l<4); [1152,1280) B2 d*2 (l==4)
__global__ __launch_bounds__(256) void k_ab_mfma(const bf16* __restrict__ h0b,
                                                 const bf16* __restrict__ Wtp,
                                                 const float* __restrict__ bias896,
                                                 char* __restrict__ ABU,
                                                 float* __restrict__ out){
  __shared__ bf16 As[128][72];
  __shared__ bf16 Bs[128][72];
  const int t = threadIdx.x;
  const int n0 = blockIdx.x * 128;
  const int gc0 = blockIdx.y * 128;
  const int lane = t & 63, wid = t >> 6;
  const int rw = wid * 32;
  const short* H  = (const short*)h0b;
  const short* Wp = (const short*)Wtp;

  #pragma unroll
  for (int i = 0; i < 4; ++i){
    int idx = t + i * 256;
    int r = idx >> 3, ko = (idx & 7) * 8;
    int n = n0 + r;
    short8v v = short8v{0,0,0,0,0,0,0,0};
    if (n < NN) v = *(const short8v*)(H + (size_t)n * 64 + ko);
    *(short8v*)&As[r][ko] = v;
  }
  #pragma unroll
  for (int i = 0; i < 4; ++i){
    int idx = t + i * 256;
    int cc = idx >> 3, ko = (idx & 7) * 8;
    *(short8v*)&Bs[cc][ko] = *(const short8v*)(Wp + (size_t)(gc0 + cc) * 64 + ko);
  }
  __syncthreads();

  f32x4 acc[2][8] = {};
  #pragma unroll
  for (int kk = 0; kk < 2; ++kk){
    short8v af0 = *(const short8v*)&As[rw + (lane & 15)][kk * 32 + (lane >> 4) * 8];
    short8v af1 = *(const short8v*)&As[rw + 16 + (lane & 15)][kk * 32 + (lane >> 4) * 8];
    #pragma unroll
    for (int j = 0; j < 8; ++j){
      short8v bfj = *(const short8v*)&Bs[j * 16 + (lane & 15)][kk * 32 + (lane >> 4) * 8];
      acc[0][j] = __builtin_amdgcn_mfma_f32_16x16x32_bf16(af0, bfj, acc[0][j], 0, 0, 0);
      acc[1][j] = __builtin_amdgcn_mfma_f32_16x16x32_bf16(af1, bfj, acc[1][j], 0, 0, 0);
    }
  }

  #pragma unroll
  for (int i = 0; i < 2; ++i){
    #pragma unroll
    for (int r = 0; r < 4; ++r){
      int n = n0 + rw + i * 16 + (lane >> 4) * 4 + r;
      if (n >= NN) continue;
      char* nb = ABU + (size_t)n * 1280;
      #pragma unroll
      for (int j = 0; j < 8; ++j){
        int gc = gc0 + j * 16 + (lane & 15);
        float v = acc[i][j][r] + bias896[gc];
        if (gc < 320){
          *(short*)(nb + gc * 2) = f2h(v);
        } else if (gc < 832){
          int q = gc - 320, dd = q >> 3, l = q & 7;
          if (l < 4)       *(short*)(nb + 640 + dd * 8 + l * 2) = f2h(v);
          else if (l == 4) *(short*)(nb + 1152 + dd * 2)        = f2h(v);
          // l in {5,6,7}: padding column, not stored
        } else {
          out[(size_t)n * 64 + (gc - 832)] = v;
        }
      }
    }
  }
}

// ---------- fused gather + posttrans GEMM ----------
// 16 waves/block, 1 node/wave gather into ag LDS; barrier; waves 0-3 run the
// 16-row x 192-col GEMM (A-frags from LDS, B from L2-resident WtKf), out += epilogue.
__global__ __launch_bounds__(1024, 2) void k_gather(const char* __restrict__ ABU,
                                                    const char* __restrict__ CTp,
                                                    const int* __restrict__ rowptr,
                                                    const int2* __restrict__ sedge,
                                                    const bf16* __restrict__ WtKf,
                                                    const float* __restrict__ amp,
                                                    const float* __restrict__ att,
                                                    float* __restrict__ out){
  __shared__ __align__(16) short ag[16][1288];   // [node-in-group][l*256+a*64+d], +8 pad
  const int t = threadIdx.x, lane = t & 63, wid = t >> 6;   // wid 0..15
  const int n = blockIdx.x * 16 + wid;          // NN % 16 == 0, always valid
  const char* AB8 = ABU + 640;
  const char* AB2 = ABU + 1152;
  const char* CT8 = CTp;
  const char* CT2 = CTp + 512;

  int r0 = rowptr[n], r1 = rowptr[n + 1];
  float s[5]  = {0.f, 0.f, 0.f, 0.f, 0.f};
  float sq[5] = {0.f, 0.f, 0.f, 0.f, 0.f};
  const _Float16 FLO = (_Float16)(-65504.f);
  const _Float16 FHI = (_Float16)( 65504.f);
  h2v mx01 = h2v{FLO, FLO}, mx23 = h2v{FLO, FLO};
  h2v mn01 = h2v{FHI, FHI}, mn23 = h2v{FHI, FHI};
  float mx4 = -65504.f, mn4 = 65504.f;

  union U8 { uint2 u; h2v h[2]; };
  const int l8 = lane * 8, l2 = lane * 2;

  for (int j = r0; j < r1; j += 4){
    int rem = r1 - j;
    int2 e0 = sedge[j];
    int2 e1 = (rem > 1) ? sedge[j + 1] : e0;
    int2 e2 = (rem > 2) ? sedge[j + 2] : e0;
    int2 e3 = (rem > 3) ? sedge[j + 3] : e0;
    U8 a0, a1, a2, a3, c0, c1, c2, c3;
    unsigned short b0, b1, b2, b3, d0, d1, d2, d3;
    a0.u = *(const uint2*)(AB8 + e0.x + l8);  b0 = *(const unsigned short*)(AB2 + e0.x + l2);
    c0.u = *(const uint2*)(CT8 + e0.y + l8);  d0 = *(const unsigned short*)(CT2 + e0.y + l2);
    a1.u = *(const uint2*)(AB8 + e1.x + l8);  b1 = *(const unsigned short*)(AB2 + e1.x + l2);
    c1.u = *(const uint2*)(CT8 + e1.y + l8);  d1 = *(const unsigned short*)(CT2 + e1.y + l2);
    a2.u = *(const uint2*)(AB8 + e2.x + l8);  b2 = *(const unsigned short*)(AB2 + e2.x + l2);
    c2.u = *(const uint2*)(CT8 + e2.y + l8);  d2 = *(const unsigned short*)(CT2 + e2.y + l2);
    a3.u = *(const uint2*)(AB8 + e3.x + l8);  b3 = *(const unsigned short*)(AB2 + e3.x + l2);
    c3.u = *(const uint2*)(CT8 + e3.y + l8);  d3 = *(const unsigned short*)(CT2 + e3.y + l2);

    #define EDGE_ACC(A, C, BL, DL) {                                \
      h2v t01 = A.h[0] + C.h[0];                                    \
      h2v t23 = A.h[1] + C.h[1];                                    \
      _Float16 hb, hd;                                              \
      __builtin_memcpy(&hb, &BL, 2);                                \
      __builtin_memcpy(&hd, &DL, 2);                                \
      float f4 = (float)(hb + hd);                                  \
      mx01 = __builtin_elementwise_max(mx01, t01);                  \
      mx23 = __builtin_elementwise_max(mx23, t23);                  \
      mn01 = __builtin_elementwise_min(mn01, t01);                  \
      mn23 = __builtin_elementwise_min(mn23, t23);                  \
      mx4 = fmaxf(mx4, f4); mn4 = fminf(mn4, f4);                   \
      float f0 = (float)t01[0], f1 = (float)t01[1];                 \
      float f2 = (float)t23[0], f3 = (float)t23[1];                 \
      s[0] += f0; sq[0] = fmaf(f0, f0, sq[0]);                      \
      s[1] += f1; sq[1] = fmaf(f1, f1, sq[1]);                      \
      s[2] += f2; sq[2] = fmaf(f2, f2, sq[2]);                      \
      s[3] += f3; sq[3] = fmaf(f3, f3, sq[3]);                      \
      s[4] += f4; sq[4] = fmaf(f4, f4, sq[4]);                      \
    }
    EDGE_ACC(a0, c0, b0, d0);
    if (rem > 1) EDGE_ACC(a1, c1, b1, d1);
    if (rem > 2) EDGE_ACC(a2, c2, b2, d2);
    if (rem > 3) EDGE_ACC(a3, c3, b3, d3);
    #undef EDGE_ACC
  }

  float mx[5] = {(float)mx01[0], (float)mx01[1], (float)mx23[0], (float)mx23[1], mx4};
  float mn[5] = {(float)mn01[0], (float)mn01[1], (float)mn23[0], (float)mn23[1], mn4};

  int d = r1 - r0;
  float degc = (float)((d > 0) ? d : 1);
  const char* nb = ABU + (size_t)n * 1280;
  #pragma unroll
  for (int l = 0; l < 5; ++l){
    _Float16 Kh; __builtin_memcpy(&Kh, nb + l * 128 + lane * 2, 2);
    float K = (float)Kh;                                  // includes pre_b
    float mean = ((float)d * K + s[l]) / degc;
    float MX = (d > 0) ? (K + mx[l]) : 0.f;
    float MN = (d > 0) ? (K + mn[l]) : 0.f;
    float mu = s[l] / degc;
    float var = fmaxf(sq[l] / degc - mu * mu, 0.f);
    float sd = sqrtf(var + EPSV);
    ag[wid][l * 256 + lane]       = f2s(mean);
    ag[wid][l * 256 + 64 + lane]  = f2s(MX);
    ag[wid][l * 256 + 128 + lane] = f2s(MN);
    ag[wid][l * 256 + 192 + lane] = f2s(sd);
  }
  __syncthreads();

  if (wid >= 4) return;   // no further barriers: legal early exit

  // ---- GEMM tail: waves 0-3, col-slice w4=wid; A-frags from ag LDS ----
  const char* pb = (const char*)WtKf + wid * 1024 + lane * 16;
  const short* agrow = &ag[lane & 15][(lane >> 4) * 8];
  f32x4 acc[3] = {};
  short8v Bx[3], By[3];

  #define LOADB(dst, sidx) { \
    _Pragma("unroll") for (int g = 0; g < 3; ++g) \
      dst[g] = *(const short8v*)(pb + (size_t)(sidx) * 12288 + g * 4096); }
  #define MFMA3(af, B) { \
    _Pragma("unroll") for (int g = 0; g < 3; ++g) \
      acc[g] = __builtin_amdgcn_mfma_f32_16x16x32_bf16(af, B[g], acc[g], 0, 0, 0); }

  LOADB(Bx, 0);
  for (int k = 0; k < 19; ++k){
    LOADB(By, 2 * k + 1);
    short8v af0 = *(const short8v*)(agrow + (2 * k) * 32);
    MFMA3(af0, Bx);
    LOADB(Bx, 2 * k + 2);
    short8v af1 = *(const short8v*)(agrow + (2 * k + 1) * 32);
    MFMA3(af1, By);
  }
  LOADB(By, 39);
  {
    short8v af0 = *(const short8v*)(agrow + 38 * 32);
    MFMA3(af0, Bx);
    short8v af1 = *(const short8v*)(agrow + 39 * 32);
    MFMA3(af1, By);
  }
  #undef LOADB
  #undef MFMA3

  // epilogue: out += U + amp*V + att*W  (C/D: col=lane&15, row=(lane>>4)*4+reg)
  #pragma unroll
  for (int r = 0; r < 4; ++r){
    int row = (lane >> 4) * 4 + r;
    int nn = blockIdx.x * 16 + row;
    float am = amp[nn], at = att[nn];
    int c = wid * 16 + (lane & 15);
    out[(size_t)nn * 64 + c] += acc[0][r] + am * acc[1][r] + at * acc[2][r];
  }
}

extern "C" void kernel_launch(void* const* d_in, const int* in_sizes, int n_in,
                              void* d_out, int out_size, void* d_ws, size_t ws_size,
                              hipStream_t stream){
  const int*   x     = (const int*)d_in[0];
  const int*   ei    = (const int*)d_in[1];
  const int*   ea    = (const int*)d_in[2];
  const float* aemb  = (const float*)d_in[3];
  const float* bemb  = (const float*)d_in[4];
  const float* preW  = (const float*)d_in[5];
  const float* preb  = (const float*)d_in[6];
  const float* postW = (const float*)d_in[7];
  const float* postb = (const float*)d_in[8];
  float* out = (float*)d_out;

  char* p = (char*)d_ws;
  auto alloc = [&](size_t bytes) -> char* {
    char* r = p;
    p += (bytes + 255) & ~(size_t)255;
    return r;
  };
  bf16*      h0b     = (bf16*)     alloc((size_t)NN * 64 * 2);
  char*      ABU     = (char*)     alloc((size_t)NN * 1280);
  int*       deg     = (int*)      alloc((size_t)NN * 4);
  int*       rowptr  = (int*)      alloc((size_t)(NN + 1) * 4);
  int*       cursor  = (int*)      alloc((size_t)NN * 4);
  float*     amp     = (float*)    alloc((size_t)NN * 4);
  float*     att     = (float*)    alloc((size_t)NN * 4);
  int*       code    = (int*)      alloc((size_t)NE * 4);
  int2*      sedge   = (int2*)     alloc((size_t)NE * 8);
  _Float16*  CTp     = (_Float16*) alloc((size_t)512 * 640);
  int*       part    = (int*)      alloc((size_t)256 * 4);
  bf16*      WtKf    = (bf16*)     alloc((size_t)40 * 12 * 64 * 8 * 2);
  bf16*      Wtp     = (bf16*)     alloc((size_t)896 * 64 * 2);
  float*     bias896 = (float*)    alloc((size_t)896 * 4);
  if ((size_t)(p - (char*)d_ws) > ws_size) return;

  hipMemsetAsync(deg, 0, (size_t)NN * 4, stream);
  hipMemsetAsync(cursor, 0, (size_t)NN * 4, stream);

  k_h0<<<dim3((NN * 64 + 255) / 256), 256, 0, stream>>>(x, aemb, h0b);
  k_deg_code<<<dim3((NE + 255) / 256), 256, 0, stream>>>(ei, ea, deg, code);
  int nblk = (NN + 255) / 256;
  k_scan1<<<dim3(nblk), 256, 0, stream>>>(deg, rowptr, part);
  k_scan2<<<dim3(1), 256, 0, stream>>>(part, nblk);
  k_scan3<<<dim3(nblk), 256, 0, stream>>>(rowptr, part, deg, amp, att);
  k_scatter<<<dim3((NE + 255) / 256), 256, 0, stream>>>(ei, code, rowptr, cursor, sedge);
  k_ctab<<<dim3(512, 5), 64, 0, stream>>>(bemb, preW, CTp);
  k_wtk<<<dim3((40 * 12 * 64 * 8 + 255) / 256), 256, 0, stream>>>(postW, WtKf);
  k_wtpre896<<<dim3((896 * 64 + 255) / 256), 256, 0, stream>>>(preW, preb, postW, postb,
                                                               Wtp, bias896);
  k_ab_mfma<<<dim3((NN + 127) / 128, 7), 256, 0, stream>>>(h0b, Wtp, bias896, ABU, out);
  k_gather<<<dim3(NN / 16), 1024, 0, stream>>>(ABU, (const char*)CTp, rowptr, sedge,
                                               WtKf, amp, att, out);
}